// Round 1
// baseline (1832.377 us; speedup 1.0000x reference)
//
#include <hip/hip_runtime.h>
#include <hip/hip_bf16.h>

// Problem constants
constexpr int A_ = 8;       // agents
constexpr int B_ = 32768;   // batch
constexpr int O_ = 256;     // obs
constexpr int C_ = 64;      // actions
constexpr int F_ = O_ + C_; // 320
constexpr int E_ = 128;     // embedding
constexpr int NCH = 128;    // stats chunks
constexpr int CHROWS = B_ / NCH; // 256
constexpr int RB = 32;      // rows per block tile

__device__ __forceinline__ float lrelu(float x){ return x >= 0.0f ? x : 0.01f * x; }

// ---------------- Stage 0: BN stats (deterministic two-stage) ----------------
__global__ void k_stats_partial(const float* __restrict__ obs,
                                const float* __restrict__ act,
                                float* __restrict__ psum, float* __restrict__ psq){
  const int f  = threadIdx.x;      // 0..319
  const int ch = blockIdx.x;       // 0..NCH-1
  const int a  = blockIdx.y;
  const size_t b0 = (size_t)ch * CHROWS;
  float s = 0.f, q = 0.f;
  if (f < O_) {
    const float* p = obs + ((size_t)a * B_ + b0) * O_ + f;
    for (int i = 0; i < CHROWS; ++i){ float x = p[(size_t)i * O_]; s += x; q += x * x; }
  } else {
    const float* p = act + ((size_t)a * B_ + b0) * C_ + (f - O_);
    for (int i = 0; i < CHROWS; ++i){ float x = p[(size_t)i * C_]; s += x; q += x * x; }
  }
  psum[((size_t)a * NCH + ch) * F_ + f] = s;
  psq [((size_t)a * NCH + ch) * F_ + f] = q;
}

__global__ void k_stats_final(const float* __restrict__ psum, const float* __restrict__ psq,
                              float* __restrict__ zscale, float* __restrict__ zshift){
  const int f = threadIdx.x;   // 0..319
  const int a = blockIdx.x;
  float s = 0.f, q = 0.f;
  for (int ch = 0; ch < NCH; ++ch){
    s += psum[((size_t)a * NCH + ch) * F_ + f];
    q += psq [((size_t)a * NCH + ch) * F_ + f];
  }
  const float mean = s * (1.0f / B_);
  float var = q * (1.0f / B_) - mean * mean;   // biased variance (ddof=0)
  var = fmaxf(var, 0.0f);
  const float rs = rsqrtf(var + 1e-5f);
  zscale[a * F_ + f] = rs;
  zshift[a * F_ + f] = -mean * rs;
}

// ---------------- Stage 0b: fold BN gamma/beta into weights, transpose K-major ----
__global__ void k_prep(const float* __restrict__ gW, const float* __restrict__ gb,
                       const float* __restrict__ ggam, const float* __restrict__ gbet,
                       const float* __restrict__ sW, const float* __restrict__ sb,
                       const float* __restrict__ sgam, const float* __restrict__ sbet,
                       const float* __restrict__ f1W, const float* __restrict__ f2W,
                       const float* __restrict__ Vm,
                       float* __restrict__ gWt, float* __restrict__ gbp,
                       float* __restrict__ sWt, float* __restrict__ sbp,
                       float* __restrict__ f1Wt, float* __restrict__ f2Wt,
                       float* __restrict__ Vt){
  const int a = blockIdx.x, t = threadIdx.x;   // 256 threads
  // gWt[a][f][c] = gW[a][c][f] * ggam[a][f]
  for (int i = t; i < F_ * E_; i += 256){
    const int f = i / E_, c = i - f * E_;
    gWt[(size_t)a * F_ * E_ + i] = gW[(size_t)a * E_ * F_ + (size_t)c * F_ + f] * ggam[a * F_ + f];
  }
  // sWt[a][f][c] = sW[a][c][f] * sgam[a][f]
  for (int i = t; i < O_ * E_; i += 256){
    const int f = i / E_, c = i - f * E_;
    sWt[(size_t)a * O_ * E_ + i] = sW[(size_t)a * E_ * O_ + (size_t)c * O_ + f] * sgam[a * O_ + f];
  }
  // f1Wt[a][f][c] = f1W[a][c][f]   (f in 0..255)
  for (int i = t; i < 2 * E_ * E_; i += 256){
    const int f = i / E_, c = i - f * E_;
    f1Wt[(size_t)a * 2 * E_ * E_ + i] = f1W[(size_t)a * E_ * 2 * E_ + (size_t)c * 2 * E_ + f];
  }
  // f2Wt[a][k][c] = f2W[a][c][k]
  for (int i = t; i < E_ * C_; i += 256){
    const int k = i / C_, c = i - k * C_;
    f2Wt[(size_t)a * E_ * C_ + i] = f2W[(size_t)a * C_ * E_ + (size_t)c * E_ + k];
  }
  // folded biases: b' = b + beta @ W^T
  if (t < E_){
    float ag = gb[a * E_ + t];
    for (int f = 0; f < F_; ++f) ag += gbet[a * F_ + f] * gW[(size_t)a * E_ * F_ + (size_t)t * F_ + f];
    gbp[a * E_ + t] = ag;
    float as = sb[a * E_ + t];
    for (int f = 0; f < O_; ++f) as += sbet[a * O_ + f] * sW[(size_t)a * E_ * O_ + (size_t)t * O_ + f];
    sbp[a * E_ + t] = as;
  }
  // Vt[e][j] = V[j][e]  (j = h*Dh+d flattened; shared across agents)
  if (a == 0){
    for (int i = t; i < E_ * E_; i += 256){
      const int e = i / E_, j = i - e * E_;
      Vt[i] = Vm[(size_t)j * E_ + e];
    }
  }
}

// ---------------- Stage A: z -> e -> {si, v} ----------------
__global__ __launch_bounds__(256) void k_stageA(
    const float* __restrict__ obs, const float* __restrict__ act,
    const float* __restrict__ zscale, const float* __restrict__ zshift,
    const float* __restrict__ gWt, const float* __restrict__ gbp,
    const float* __restrict__ sWt, const float* __restrict__ sbp,
    const float* __restrict__ Vt,
    __hip_bfloat16* __restrict__ si_bf, __hip_bfloat16* __restrict__ v_bf){
  __shared__ float z[RB][F_];    // 40 KB
  __shared__ float et[RB][E_];   // 16 KB
  const int a  = blockIdx.y;
  const int r0 = blockIdx.x * RB;
  const int t  = threadIdx.x;

  // phase 1: load + standardize (BN gamma/beta folded into weights)
  for (int i = t; i < RB * F_; i += 256){
    const int r = i / F_, f = i - r * F_;
    const size_t b = (size_t)(r0 + r);
    const float raw = (f < O_) ? obs[((size_t)a * B_ + b) * O_ + f]
                               : act[((size_t)a * B_ + b) * C_ + (f - O_)];
    z[r][f] = raw * zscale[a * F_ + f] + zshift[a * F_ + f];
  }
  __syncthreads();

  const int c0 = (t & 63) * 2;   // output col pair
  const int rh = t >> 6;         // 0..3 -> rows rh*8 .. rh*8+7

  float acc[8][2];
  // ---- e = lrelu(z @ gWt + gbp), K = 320 ----
  #pragma unroll
  for (int j = 0; j < 8; ++j){ acc[j][0] = 0.f; acc[j][1] = 0.f; }
  for (int k0 = 0; k0 < F_; k0 += 4){
    float4 zv[8];
    #pragma unroll
    for (int j = 0; j < 8; ++j) zv[j] = *(const float4*)&z[rh * 8 + j][k0];
    #pragma unroll
    for (int kk = 0; kk < 4; ++kk){
      const float2 w = *(const float2*)&gWt[((size_t)a * F_ + (k0 + kk)) * E_ + c0];
      #pragma unroll
      for (int j = 0; j < 8; ++j){
        const float zz = (&zv[j].x)[kk];
        acc[j][0] = fmaf(zz, w.x, acc[j][0]);
        acc[j][1] = fmaf(zz, w.y, acc[j][1]);
      }
    }
  }
  {
    const float b0 = gbp[a * E_ + c0], b1 = gbp[a * E_ + c0 + 1];
    #pragma unroll
    for (int j = 0; j < 8; ++j){
      et[rh * 8 + j][c0]     = lrelu(acc[j][0] + b0);
      et[rh * 8 + j][c0 + 1] = lrelu(acc[j][1] + b1);
    }
  }
  __syncthreads();

  // ---- si = lrelu(z[:, :256] @ sWt + sbp), K = 256 ----
  #pragma unroll
  for (int j = 0; j < 8; ++j){ acc[j][0] = 0.f; acc[j][1] = 0.f; }
  for (int k0 = 0; k0 < O_; k0 += 4){
    float4 zv[8];
    #pragma unroll
    for (int j = 0; j < 8; ++j) zv[j] = *(const float4*)&z[rh * 8 + j][k0];
    #pragma unroll
    for (int kk = 0; kk < 4; ++kk){
      const float2 w = *(const float2*)&sWt[((size_t)a * O_ + (k0 + kk)) * E_ + c0];
      #pragma unroll
      for (int j = 0; j < 8; ++j){
        const float zz = (&zv[j].x)[kk];
        acc[j][0] = fmaf(zz, w.x, acc[j][0]);
        acc[j][1] = fmaf(zz, w.y, acc[j][1]);
      }
    }
  }
  {
    const float b0 = sbp[a * E_ + c0], b1 = sbp[a * E_ + c0 + 1];
    #pragma unroll
    for (int j = 0; j < 8; ++j){
      const size_t row = (size_t)a * B_ + (size_t)(r0 + rh * 8 + j);
      __hip_bfloat162 p;
      p.x = __float2bfloat16(lrelu(acc[j][0] + b0));
      p.y = __float2bfloat16(lrelu(acc[j][1] + b1));
      *(__hip_bfloat162*)&si_bf[row * E_ + c0] = p;
    }
  }

  // ---- v = lrelu(et @ Vt), K = 128, no bias ----
  #pragma unroll
  for (int j = 0; j < 8; ++j){ acc[j][0] = 0.f; acc[j][1] = 0.f; }
  for (int k0 = 0; k0 < E_; k0 += 4){
    float4 ev[8];
    #pragma unroll
    for (int j = 0; j < 8; ++j) ev[j] = *(const float4*)&et[rh * 8 + j][k0];
    #pragma unroll
    for (int kk = 0; kk < 4; ++kk){
      const float2 w = *(const float2*)&Vt[(size_t)(k0 + kk) * E_ + c0];
      #pragma unroll
      for (int j = 0; j < 8; ++j){
        const float ee = (&ev[j].x)[kk];
        acc[j][0] = fmaf(ee, w.x, acc[j][0]);
        acc[j][1] = fmaf(ee, w.y, acc[j][1]);
      }
    }
  }
  #pragma unroll
  for (int j = 0; j < 8; ++j){
    const size_t row = (size_t)a * B_ + (size_t)(r0 + rh * 8 + j);
    __hip_bfloat162 p;
    p.x = __float2bfloat16(lrelu(acc[j][0]));
    p.y = __float2bfloat16(lrelu(acc[j][1]));
    *(__hip_bfloat162*)&v_bf[row * E_ + c0] = p;
  }
}

// ---------------- Stage B: vsum over agents ----------------
__global__ void k_vsum(const __hip_bfloat16* __restrict__ v_bf, float* __restrict__ vsum){
  const size_t idx = (size_t)blockIdx.x * 256 + threadIdx.x;  // < B_*E_
  float s = 0.f;
  #pragma unroll
  for (int a = 0; a < A_; ++a) s += __bfloat162float(v_bf[(size_t)a * B_ * E_ + idx]);
  vsum[idx] = s;
}

// ---------------- Stage C: x=vsum-v || si -> h -> q -> argmax gather ----------------
__global__ __launch_bounds__(256) void k_stageC(
    const float* __restrict__ act,
    const __hip_bfloat16* __restrict__ si_bf,
    const __hip_bfloat16* __restrict__ v_bf,
    const float* __restrict__ vsum,
    const float* __restrict__ f1Wt, const float* __restrict__ f1b,
    const float* __restrict__ f2Wt, const float* __restrict__ f2b,
    float* __restrict__ out){
  __shared__ float xs[RB][2 * E_];  // 32 KB
  __shared__ float ht[RB][E_];      // 16 KB
  __shared__ float qt[RB][C_];      // 8 KB
  __shared__ float at[RB][C_ + 1];  // 8.125 KB (padded vs bank conflicts)
  const int a = blockIdx.y, r0 = blockIdx.x * RB, t = threadIdx.x;

  for (int i = t; i < RB * 2 * E_; i += 256){
    const int r = i >> 8, f = i & 255;
    const size_t b = (size_t)(r0 + r);
    float val;
    if (f < E_) val = vsum[b * E_ + f] - __bfloat162float(v_bf[((size_t)a * B_ + b) * E_ + f]);
    else        val = __bfloat162float(si_bf[((size_t)a * B_ + b) * E_ + (f - E_)]);
    xs[r][f] = val;
  }
  for (int i = t; i < RB * C_; i += 256){
    const int r = i >> 6, c = i & 63;
    at[r][c] = act[((size_t)a * B_ + (size_t)(r0 + r)) * C_ + c];
  }
  __syncthreads();

  const int c0 = (t & 63) * 2;
  const int rh = t >> 6;
  float acc[8][2];
  #pragma unroll
  for (int j = 0; j < 8; ++j){ acc[j][0] = 0.f; acc[j][1] = 0.f; }
  for (int k0 = 0; k0 < 2 * E_; k0 += 4){
    float4 xv[8];
    #pragma unroll
    for (int j = 0; j < 8; ++j) xv[j] = *(const float4*)&xs[rh * 8 + j][k0];
    #pragma unroll
    for (int kk = 0; kk < 4; ++kk){
      const float2 w = *(const float2*)&f1Wt[((size_t)a * 2 * E_ + (k0 + kk)) * E_ + c0];
      #pragma unroll
      for (int j = 0; j < 8; ++j){
        const float xx = (&xv[j].x)[kk];
        acc[j][0] = fmaf(xx, w.x, acc[j][0]);
        acc[j][1] = fmaf(xx, w.y, acc[j][1]);
      }
    }
  }
  {
    const float b0 = f1b[a * E_ + c0], b1 = f1b[a * E_ + c0 + 1];
    #pragma unroll
    for (int j = 0; j < 8; ++j){
      ht[rh * 8 + j][c0]     = lrelu(acc[j][0] + b0);
      ht[rh * 8 + j][c0 + 1] = lrelu(acc[j][1] + b1);
    }
  }
  __syncthreads();

  // q: K=128, N=64. 8 outputs/thread: 4 rows x 2 cols.
  const int cq = (t & 31) * 2;
  const int rq = t >> 5;   // 0..7 -> rows rq*4 .. rq*4+3
  float qacc[4][2];
  #pragma unroll
  for (int j = 0; j < 4; ++j){ qacc[j][0] = 0.f; qacc[j][1] = 0.f; }
  for (int k0 = 0; k0 < E_; k0 += 4){
    float4 hv[4];
    #pragma unroll
    for (int j = 0; j < 4; ++j) hv[j] = *(const float4*)&ht[rq * 4 + j][k0];
    #pragma unroll
    for (int kk = 0; kk < 4; ++kk){
      const float2 w = *(const float2*)&f2Wt[((size_t)a * E_ + (k0 + kk)) * C_ + cq];
      #pragma unroll
      for (int j = 0; j < 4; ++j){
        const float hh = (&hv[j].x)[kk];
        qacc[j][0] = fmaf(hh, w.x, qacc[j][0]);
        qacc[j][1] = fmaf(hh, w.y, qacc[j][1]);
      }
    }
  }
  {
    const float b0 = f2b[a * C_ + cq], b1 = f2b[a * C_ + cq + 1];
    #pragma unroll
    for (int j = 0; j < 4; ++j){
      qt[rq * 4 + j][cq]     = qacc[j][0] + b0;
      qt[rq * 4 + j][cq + 1] = qacc[j][1] + b1;
    }
  }
  __syncthreads();

  // argmax over actions (first max, np semantics) + gather
  if (t < RB){
    float best = at[t][0]; int bi = 0;
    for (int c = 1; c < C_; ++c){
      const float v = at[t][c];
      if (v > best){ best = v; bi = c; }
    }
    out[(size_t)a * B_ + (size_t)(r0 + t)] = qt[t][bi];
  }
}

extern "C" void kernel_launch(void* const* d_in, const int* in_sizes, int n_in,
                              void* d_out, int out_size, void* d_ws, size_t ws_size,
                              hipStream_t stream) {
  const float* obs  = (const float*)d_in[0];
  const float* act  = (const float*)d_in[1];
  const float* ggam = (const float*)d_in[2];
  const float* gbet = (const float*)d_in[3];
  const float* gW   = (const float*)d_in[4];
  const float* gb   = (const float*)d_in[5];
  const float* sgam = (const float*)d_in[6];
  const float* sbet = (const float*)d_in[7];
  const float* sW   = (const float*)d_in[8];
  const float* sb   = (const float*)d_in[9];
  const float* f1W  = (const float*)d_in[10];
  const float* f1b  = (const float*)d_in[11];
  const float* f2W  = (const float*)d_in[12];
  const float* f2b  = (const float*)d_in[13];
  // d_in[14] = Wq, d_in[15] = Wk: dead (softmax over length-1 axis == 1.0)
  const float* Vm   = (const float*)d_in[16];
  float* out = (float*)d_out;

  char* base = (char*)d_ws;
  size_t off = 0;
  auto alloc = [&](size_t bytes) -> void* {
    off = (off + 255) & ~(size_t)255;
    void* p = base + off;
    off += bytes;
    return p;
  };
  float* psum   = (float*)alloc((size_t)A_ * NCH * F_ * 4);
  float* psq    = (float*)alloc((size_t)A_ * NCH * F_ * 4);
  float* zscale = (float*)alloc((size_t)A_ * F_ * 4);
  float* zshift = (float*)alloc((size_t)A_ * F_ * 4);
  float* gWt    = (float*)alloc((size_t)A_ * F_ * E_ * 4);
  float* gbp    = (float*)alloc((size_t)A_ * E_ * 4);
  float* sWt    = (float*)alloc((size_t)A_ * O_ * E_ * 4);
  float* sbp    = (float*)alloc((size_t)A_ * E_ * 4);
  float* f1Wt   = (float*)alloc((size_t)A_ * 2 * E_ * E_ * 4);
  float* f2Wt   = (float*)alloc((size_t)A_ * E_ * C_ * 4);
  float* Vt     = (float*)alloc((size_t)E_ * E_ * 4);
  float* vsum   = (float*)alloc((size_t)B_ * E_ * 4);
  __hip_bfloat16* si_bf = (__hip_bfloat16*)alloc((size_t)A_ * B_ * E_ * 2);
  __hip_bfloat16* v_bf  = (__hip_bfloat16*)alloc((size_t)A_ * B_ * E_ * 2);
  (void)ws_size; (void)in_sizes; (void)n_in; (void)out_size;

  k_stats_partial<<<dim3(NCH, A_), 320, 0, stream>>>(obs, act, psum, psq);
  k_stats_final<<<A_, F_, 0, stream>>>(psum, psq, zscale, zshift);
  k_prep<<<A_, 256, 0, stream>>>(gW, gb, ggam, gbet, sW, sb, sgam, sbet,
                                 f1W, f2W, Vm, gWt, gbp, sWt, sbp, f1Wt, f2Wt, Vt);
  k_stageA<<<dim3(B_ / RB, A_), 256, 0, stream>>>(obs, act, zscale, zshift,
                                                  gWt, gbp, sWt, sbp, Vt, si_bf, v_bf);
  k_vsum<<<(B_ * E_) / 256, 256, 0, stream>>>(v_bf, vsum);
  k_stageC<<<dim3(B_ / RB, A_), 256, 0, stream>>>(act, si_bf, v_bf, vsum,
                                                  f1Wt, f1b, f2Wt, f2b, out);
}

// Round 2
// 616.182 us; speedup vs baseline: 2.9738x; 2.9738x over previous
//
#include <hip/hip_runtime.h>
#include <hip/hip_bf16.h>
#include <stdint.h>

constexpr int A_ = 8, B_ = 32768, O_ = 256, C_ = 64, F_ = 320, E_ = 128;
constexpr int NCH = 128, CHROWS = B_ / NCH;
constexpr int NT_ = B_ / 16;      // row-tiles of 16 per agent
constexpr int KS_ES = 10;         // k-steps for e|si GEMM (K=320)

typedef __attribute__((ext_vector_type(8))) __bf16 bf16x8;
typedef __attribute__((ext_vector_type(4))) float f32x4;

__device__ __forceinline__ float lrelu(float x){ return x >= 0.f ? x : 0.01f * x; }
__device__ __forceinline__ f32x4 mfma16(bf16x8 a, bf16x8 b, f32x4 c){
  return __builtin_amdgcn_mfma_f32_16x16x32_bf16(a, b, c, 0, 0, 0);
}

// ---------------- Stage 0: BN stats (deterministic two-stage) ----------------
__global__ void k_stats_partial(const float* __restrict__ obs,
                                const float* __restrict__ act,
                                float* __restrict__ psum, float* __restrict__ psq){
  const int f = threadIdx.x, ch = blockIdx.x, a = blockIdx.y;
  const size_t b0 = (size_t)ch * CHROWS;
  float s = 0.f, q = 0.f;
  if (f < O_){
    const float* p = obs + ((size_t)a*B_ + b0)*O_ + f;
    for (int i = 0; i < CHROWS; ++i){ float x = p[(size_t)i*O_]; s += x; q += x*x; }
  } else {
    const float* p = act + ((size_t)a*B_ + b0)*C_ + (f - O_);
    for (int i = 0; i < CHROWS; ++i){ float x = p[(size_t)i*C_]; s += x; q += x*x; }
  }
  psum[((size_t)a*NCH + ch)*F_ + f] = s;
  psq [((size_t)a*NCH + ch)*F_ + f] = q;
}

__global__ void k_stats_final(const float* __restrict__ psum, const float* __restrict__ psq,
                              float* __restrict__ zscale, float* __restrict__ zshift){
  const int f = threadIdx.x, a = blockIdx.x;
  float s = 0.f, q = 0.f;
  for (int ch = 0; ch < NCH; ++ch){
    s += psum[((size_t)a*NCH + ch)*F_ + f];
    q += psq [((size_t)a*NCH + ch)*F_ + f];
  }
  const float mean = s * (1.0f / B_);
  float var = q * (1.0f / B_) - mean * mean;
  var = fmaxf(var, 0.0f);
  const float rs = rsqrtf(var + 1e-5f);
  zscale[a*F_ + f] = rs;
  zshift[a*F_ + f] = -mean * rs;
}

// ---- pack weights into MFMA B-fragment order (bf16), fold BN gamma; fold beta into bias ----
// Bp  : [a][ks 0..9][nt 0..15][lane 0..63][e 0..7]  (e|si combined, N=256, K=320; si zero-padded K>=256)
// B1p : [a][ks 0..7][nt 0..7][lane][e]              (f1, N=128, K=256)
// B2p : [a][ks 0..3][nt 0..3][lane][e]              (f2, N=64,  K=128)
// Vp  : [ks 0..3][nt 0..7][lane][e]                 (V,  N=128, K=128, shared)
__global__ void k_prep(const float* __restrict__ gW, const float* __restrict__ gb,
                       const float* __restrict__ ggam, const float* __restrict__ gbet,
                       const float* __restrict__ sW, const float* __restrict__ sb,
                       const float* __restrict__ sgam, const float* __restrict__ sbet,
                       const float* __restrict__ f1W, const float* __restrict__ f2W,
                       const float* __restrict__ Vm,
                       __bf16* __restrict__ Bp, __bf16* __restrict__ Vp,
                       __bf16* __restrict__ B1p, __bf16* __restrict__ B2p,
                       float* __restrict__ gbp, float* __restrict__ sbp){
  const int a = blockIdx.x, t = threadIdx.x;
  for (int i = t; i < KS_ES*16*512; i += 256){
    const int ks = i >> 13, rem = i & 8191;
    const int nt = rem >> 9, l = (rem >> 3) & 63, e = i & 7;
    const int n = nt*16 + (l & 15), k = ks*32 + (l >> 4)*8 + e;
    float v;
    if (n < 128)       v = gW[(size_t)a*E_*F_ + (size_t)n*F_ + k] * ggam[a*F_ + k];
    else if (k < O_)   v = sW[(size_t)a*E_*O_ + (size_t)(n-128)*O_ + k] * sgam[a*O_ + k];
    else               v = 0.f;
    Bp[(size_t)a*(KS_ES*16*512) + i] = (__bf16)v;
  }
  for (int i = t; i < 8*8*512; i += 256){
    const int ks = i >> 12, nt = (i >> 9) & 7, l = (i >> 3) & 63, e = i & 7;
    const int n = nt*16 + (l & 15), k = ks*32 + (l >> 4)*8 + e;
    B1p[(size_t)a*(8*8*512) + i] = (__bf16)f1W[(size_t)a*E_*2*E_ + (size_t)n*2*E_ + k];
  }
  for (int i = t; i < 4*4*512; i += 256){
    const int ks = i >> 11, nt = (i >> 9) & 3, l = (i >> 3) & 63, e = i & 7;
    const int n = nt*16 + (l & 15), k = ks*32 + (l >> 4)*8 + e;
    B2p[(size_t)a*(4*4*512) + i] = (__bf16)f2W[(size_t)a*C_*E_ + (size_t)n*E_ + k];
  }
  if (a == 0){
    for (int i = t; i < 4*8*512; i += 256){
      const int ks = i >> 12, nt = (i >> 9) & 7, l = (i >> 3) & 63, e = i & 7;
      const int n = nt*16 + (l & 15), k = ks*32 + (l >> 4)*8 + e;
      Vp[i] = (__bf16)Vm[(size_t)n*E_ + k];
    }
  }
  if (t < E_){
    float ag = gb[a*E_ + t];
    for (int f = 0; f < F_; ++f) ag += gbet[a*F_ + f] * gW[(size_t)a*E_*F_ + (size_t)t*F_ + f];
    gbp[a*E_ + t] = ag;
    float as = sb[a*E_ + t];
    for (int f = 0; f < O_; ++f) as += sbet[a*O_ + f] * sW[(size_t)a*E_*O_ + (size_t)t*O_ + f];
    sbp[a*E_ + t] = as;
  }
}

// ---------------- Stage A: z -> [e|si] (one MFMA GEMM, N=256) -> v ----------------
// frag-major global layout for si/v: elem = (a*NT_ + rt)*2048 + kg*128 + r*8 + e
__global__ __launch_bounds__(256, 2) void k_stageA(
    const float* __restrict__ obs, const float* __restrict__ act,
    const float* __restrict__ zscale, const float* __restrict__ zshift,
    const __bf16* __restrict__ Bp, const __bf16* __restrict__ Vp,
    const float* __restrict__ gbp, const float* __restrict__ sbp,
    __bf16* __restrict__ si_g, __bf16* __restrict__ v_g){
  __shared__ __align__(16) char smem[65536];
  char* zb0 = smem;             // z k-chunk frag-major, 8 KB
  char* zb1 = smem + 8192;
  char* wb  = smem + 16384;     // W k-step tile, 16 KB (single-buffered, reg-prefetched)
  char* et  = smem + 32768;     // e tile frag-major, 32 KB

  const int a = blockIdx.y, r0 = blockIdx.x * 128, t = threadIdx.x;
  const int w = t >> 6, l = t & 63;
  const int wr = w >> 1, wc = w & 1;
  const int lr = l & 15, lg = l >> 4;
  const int sg = t & 3, sr = t >> 2;   // staging: k-group, row

  const uint4* Bp4 = (const uint4*)(Bp + (size_t)a*(KS_ES*16*512));

  f32x4 acc[4][8] = {};

  // ---- prologue: stage ks=0 (z + W) ----
  {
    uint4 w0[4];
    #pragma unroll
    for (int i = 0; i < 4; ++i) w0[i] = Bp4[i*256 + t];
    const int k = sg*8;
    float4 s0 = *(const float4*)(zscale + a*F_ + k);
    float4 s1 = *(const float4*)(zscale + a*F_ + k + 4);
    float4 h0 = *(const float4*)(zshift + a*F_ + k);
    float4 h1 = *(const float4*)(zshift + a*F_ + k + 4);
    #pragma unroll
    for (int p = 0; p < 2; ++p){
      const int rr = sr + p*64;
      const float* src = obs + ((size_t)a*B_ + (size_t)(r0 + rr))*O_ + k;
      float4 x0 = *(const float4*)src, x1 = *(const float4*)(src + 4);
      bf16x8 zz;
      zz[0]=(__bf16)fmaf(x0.x,s0.x,h0.x); zz[1]=(__bf16)fmaf(x0.y,s0.y,h0.y);
      zz[2]=(__bf16)fmaf(x0.z,s0.z,h0.z); zz[3]=(__bf16)fmaf(x0.w,s0.w,h0.w);
      zz[4]=(__bf16)fmaf(x1.x,s1.x,h1.x); zz[5]=(__bf16)fmaf(x1.y,s1.y,h1.y);
      zz[6]=(__bf16)fmaf(x1.z,s1.z,h1.z); zz[7]=(__bf16)fmaf(x1.w,s1.w,h1.w);
      *(bf16x8*)(zb0 + (rr>>4)*1024 + sg*256 + (rr&15)*16) = zz;
    }
    #pragma unroll
    for (int i = 0; i < 4; ++i) *((uint4*)wb + i*256 + t) = w0[i];
  }
  __syncthreads();

  // ---- main loop: e|si GEMM, K=320 ----
  for (int ks = 0; ks < KS_ES; ++ks){
    char* zc = (ks & 1) ? zb1 : zb0;
    char* zn = (ks & 1) ? zb0 : zb1;
    const bool hn = (ks + 1 < KS_ES);
    uint4 wnew[4];
    float4 x0a{}, x1a{}, x0b{}, x1b{}, s0{}, s1{}, h0{}, h1{};
    if (hn){
      #pragma unroll
      for (int i = 0; i < 4; ++i) wnew[i] = Bp4[(ks+1)*1024 + i*256 + t];
      const int k = (ks+1)*32 + sg*8;
      s0 = *(const float4*)(zscale + a*F_ + k);
      s1 = *(const float4*)(zscale + a*F_ + k + 4);
      h0 = *(const float4*)(zshift + a*F_ + k);
      h1 = *(const float4*)(zshift + a*F_ + k + 4);
      if (k < O_){
        const float* src = obs + ((size_t)a*B_ + (size_t)(r0 + sr))*O_ + k;
        x0a = *(const float4*)src; x1a = *(const float4*)(src + 4);
        src += (size_t)64*O_;
        x0b = *(const float4*)src; x1b = *(const float4*)(src + 4);
      } else {
        const int kc = k - O_;
        const float* src = act + ((size_t)a*B_ + (size_t)(r0 + sr))*C_ + kc;
        x0a = *(const float4*)src; x1a = *(const float4*)(src + 4);
        src += (size_t)64*C_;
        x0b = *(const float4*)src; x1b = *(const float4*)(src + 4);
      }
    }
    // compute current k-step
    bf16x8 af[4], bfr[8];
    #pragma unroll
    for (int m = 0; m < 4; ++m)
      af[m] = *(const bf16x8*)(zc + (wr*4+m)*1024 + lg*256 + lr*16);
    #pragma unroll
    for (int n = 0; n < 8; ++n)
      bfr[n] = *(const bf16x8*)(wb + ((wc*8+n)*64 + l)*16);
    #pragma unroll
    for (int m = 0; m < 4; ++m)
      #pragma unroll
      for (int n = 0; n < 8; ++n)
        acc[m][n] = mfma16(af[m], bfr[n], acc[m][n]);
    // write staged z to other buffer
    if (hn){
      bf16x8 za, zbv;
      za[0]=(__bf16)fmaf(x0a.x,s0.x,h0.x); za[1]=(__bf16)fmaf(x0a.y,s0.y,h0.y);
      za[2]=(__bf16)fmaf(x0a.z,s0.z,h0.z); za[3]=(__bf16)fmaf(x0a.w,s0.w,h0.w);
      za[4]=(__bf16)fmaf(x1a.x,s1.x,h1.x); za[5]=(__bf16)fmaf(x1a.y,s1.y,h1.y);
      za[6]=(__bf16)fmaf(x1a.z,s1.z,h1.z); za[7]=(__bf16)fmaf(x1a.w,s1.w,h1.w);
      *(bf16x8*)(zn + (sr>>4)*1024 + sg*256 + (sr&15)*16) = za;
      zbv[0]=(__bf16)fmaf(x0b.x,s0.x,h0.x); zbv[1]=(__bf16)fmaf(x0b.y,s0.y,h0.y);
      zbv[2]=(__bf16)fmaf(x0b.z,s0.z,h0.z); zbv[3]=(__bf16)fmaf(x0b.w,s0.w,h0.w);
      zbv[4]=(__bf16)fmaf(x1b.x,s1.x,h1.x); zbv[5]=(__bf16)fmaf(x1b.y,s1.y,h1.y);
      zbv[6]=(__bf16)fmaf(x1b.z,s1.z,h1.z); zbv[7]=(__bf16)fmaf(x1b.w,s1.w,h1.w);
      *(bf16x8*)(zn + ((sr+64)>>4)*1024 + sg*256 + (sr&15)*16) = zbv;
    }
    __syncthreads();                 // all reads of wb/zc done, z writes visible
    if (hn){
      #pragma unroll
      for (int i = 0; i < 4; ++i) *((uint4*)wb + i*256 + t) = wnew[i];
    }
    __syncthreads();                 // wb ready
  }

  // ---- epilogue: stage Vp into smem[0..32KB), e -> LDS (frag-major), si -> global ----
  uint4 vw[8];
  #pragma unroll
  for (int i = 0; i < 8; ++i) vw[i] = *((const uint4*)Vp + i*256 + t);

  if (wc == 0){
    #pragma unroll
    for (int n = 0; n < 8; ++n){
      const int col = n*16 + lr;
      const float bias = gbp[a*E_ + col];
      const int kg = col >> 3, e = col & 7;
      #pragma unroll
      for (int m = 0; m < 4; ++m){
        const int mt = wr*4 + m;
        #pragma unroll
        for (int j = 0; j < 4; ++j)
          *(__bf16*)(et + mt*4096 + kg*256 + (lg*4+j)*16 + e*2) =
              (__bf16)lrelu(acc[m][n][j] + bias);
      }
    }
  } else {
    #pragma unroll
    for (int n = 0; n < 8; ++n){
      const int scol = n*16 + lr;
      const float bias = sbp[a*E_ + scol];
      const int kg = scol >> 3, e = scol & 7;
      #pragma unroll
      for (int m = 0; m < 4; ++m){
        const int rt = (r0 >> 4) + wr*4 + m;
        __bf16* dst = si_g + ((size_t)a*NT_ + rt)*2048 + kg*128 + e;
        #pragma unroll
        for (int j = 0; j < 4; ++j)
          dst[(lg*4+j)*8] = (__bf16)lrelu(acc[m][n][j] + bias);
      }
    }
  }
  #pragma unroll
  for (int i = 0; i < 8; ++i) *((uint4*)smem + i*256 + t) = vw[i];
  __syncthreads();

  // ---- v-GEMM: v = lrelu(et @ V^T), K=128, N=128 ----
  f32x4 vacc[4][4] = {};
  #pragma unroll
  for (int ks = 0; ks < 4; ++ks){
    bf16x8 va[4], vb[4];
    #pragma unroll
    for (int m = 0; m < 4; ++m)
      va[m] = *(const bf16x8*)(et + (wr*4+m)*4096 + (ks*4+lg)*256 + lr*16);
    #pragma unroll
    for (int n = 0; n < 4; ++n)
      vb[n] = *(const bf16x8*)(smem + ((ks*8 + wc*4 + n)*64 + l)*16);
    #pragma unroll
    for (int m = 0; m < 4; ++m)
      #pragma unroll
      for (int n = 0; n < 4; ++n)
        vacc[m][n] = mfma16(va[m], vb[n], vacc[m][n]);
  }
  #pragma unroll
  for (int n = 0; n < 4; ++n){
    const int col = (wc*4+n)*16 + lr;
    const int kg = col >> 3, e = col & 7;
    #pragma unroll
    for (int m = 0; m < 4; ++m){
      const int rt = (r0 >> 4) + wr*4 + m;
      __bf16* dst = v_g + ((size_t)a*NT_ + rt)*2048 + kg*128 + e;
      #pragma unroll
      for (int j = 0; j < 4; ++j)
        dst[(lg*4+j)*8] = (__bf16)lrelu(vacc[m][n][j]);
    }
  }
}

// ---------------- vsum over agents (frag-major elementwise) ----------------
__global__ void k_vsum(const __bf16* __restrict__ v_g, float* __restrict__ vsum){
  const size_t i = (size_t)blockIdx.x*256 + threadIdx.x;   // uint4 chunk index
  const size_t chunks = (size_t)B_*E_/8;
  bf16x8 s8[1];
  float s[8] = {0,0,0,0,0,0,0,0};
  #pragma unroll
  for (int a = 0; a < A_; ++a){
    bf16x8 u = *((const bf16x8*)v_g + (size_t)a*chunks + i);
    #pragma unroll
    for (int e = 0; e < 8; ++e) s[e] += (float)u[e];
  }
  (void)s8;
  float4 o0 = {s[0],s[1],s[2],s[3]}, o1 = {s[4],s[5],s[6],s[7]};
  *((float4*)vsum + i*2)     = o0;
  *((float4*)vsum + i*2 + 1) = o1;
}

// ---------------- argmax(action) per row ----------------
__global__ void k_ids(const float* __restrict__ act, int* __restrict__ ids){
  const int t = threadIdx.x;
  const size_t row = (size_t)blockIdx.x*16 + (t >> 4);
  const int j = t & 15;
  float4 v = *((const float4*)act + row*16 + j);
  float best = v.x; int bi = j*4;
  if (v.y > best){ best = v.y; bi = j*4+1; }
  if (v.z > best){ best = v.z; bi = j*4+2; }
  if (v.w > best){ best = v.w; bi = j*4+3; }
  #pragma unroll
  for (int m = 1; m < 16; m <<= 1){
    float ob = __shfl_xor(best, m, 64);
    int oi = __shfl_xor(bi, m, 64);
    if (ob > best || (ob == best && oi < bi)){ best = ob; bi = oi; }
  }
  if (j == 0) ids[row] = bi;
}

// ---------------- Stage C: x=[vsum-v | si] -> h -> q -> gather ----------------
__global__ __launch_bounds__(256, 3) void k_stageC(
    const __bf16* __restrict__ si_g, const __bf16* __restrict__ v_g,
    const float* __restrict__ vsum,
    const __bf16* __restrict__ B1p, const __bf16* __restrict__ B2p,
    const float* __restrict__ f1b, const float* __restrict__ f2b,
    const int* __restrict__ ids, float* __restrict__ out){
  __shared__ __align__(16) char smem[49152];
  char* harea = smem;            // 32 KB: h frag-major, later q[128][64] f32
  char* db0 = smem + 32768;      // 8 KB
  char* db1 = smem + 40960;      // 8 KB

  const int a = blockIdx.y, r0 = blockIdx.x * 128, t = threadIdx.x;
  const int w = t >> 6, l = t & 63;
  const int wr = w >> 1, wc = w & 1;
  const int lr = l & 15, lg = l >> 4;
  const uint4* B14 = (const uint4*)(B1p + (size_t)a*(8*8*512));
  const uint4* B24 = (const uint4*)(B2p + (size_t)a*(4*4*512));

  f32x4 acc[4][4] = {};
  {
    uint4 w0[2];
    #pragma unroll
    for (int i = 0; i < 2; ++i) w0[i] = B14[i*256 + t];
    #pragma unroll
    for (int i = 0; i < 2; ++i) *((uint4*)db0 + i*256 + t) = w0[i];
  }
  __syncthreads();

  for (int ks = 0; ks < 8; ++ks){
    char* cur = (ks & 1) ? db1 : db0;
    char* nxt = (ks & 1) ? db0 : db1;
    const bool hn = (ks < 7);
    uint4 w1[2];
    if (hn){
      #pragma unroll
      for (int i = 0; i < 2; ++i) w1[i] = B14[(ks+1)*512 + i*256 + t];
    }
    bf16x8 af[4];
    #pragma unroll
    for (int m = 0; m < 4; ++m){
      const int rt = (r0 >> 4) + wr*4 + m;
      if (ks < 4){
        const int kg = ks*4 + lg;
        const float* vs = vsum + (size_t)rt*2048 + kg*128 + lr*8;
        float4 f0 = *(const float4*)vs, f1v = *(const float4*)(vs + 4);
        bf16x8 vv = *((const bf16x8*)(v_g + ((size_t)a*NT_ + rt)*2048 + kg*128 + lr*8));
        bf16x8 r;
        r[0]=(__bf16)(f0.x-(float)vv[0]); r[1]=(__bf16)(f0.y-(float)vv[1]);
        r[2]=(__bf16)(f0.z-(float)vv[2]); r[3]=(__bf16)(f0.w-(float)vv[3]);
        r[4]=(__bf16)(f1v.x-(float)vv[4]); r[5]=(__bf16)(f1v.y-(float)vv[5]);
        r[6]=(__bf16)(f1v.z-(float)vv[6]); r[7]=(__bf16)(f1v.w-(float)vv[7]);
        af[m] = r;
      } else {
        const int kg = (ks-4)*4 + lg;
        af[m] = *((const bf16x8*)(si_g + ((size_t)a*NT_ + rt)*2048 + kg*128 + lr*8));
      }
    }
    bf16x8 bfr[4];
    #pragma unroll
    for (int n = 0; n < 4; ++n)
      bfr[n] = *(const bf16x8*)(cur + ((wc*4+n)*64 + l)*16);
    #pragma unroll
    for (int m = 0; m < 4; ++m)
      #pragma unroll
      for (int n = 0; n < 4; ++n)
        acc[m][n] = mfma16(af[m], bfr[n], acc[m][n]);
    if (hn){
      #pragma unroll
      for (int i = 0; i < 2; ++i) *((uint4*)nxt + i*256 + t) = w1[i];
    }
    __syncthreads();
  }

  // h epilogue -> harea (frag-major); stage f2 into db area; one barrier
  uint4 wf2[4];
  #pragma unroll
  for (int i = 0; i < 4; ++i) wf2[i] = B24[i*256 + t];
  #pragma unroll
  for (int n = 0; n < 4; ++n){
    const int col = (wc*4+n)*16 + lr;
    const float bias = f1b[a*E_ + col];
    const int kg = col >> 3, e = col & 7;
    #pragma unroll
    for (int m = 0; m < 4; ++m)
      #pragma unroll
      for (int j = 0; j < 4; ++j)
        *(__bf16*)(harea + (wr*4+m)*4096 + kg*256 + (lg*4+j)*16 + e*2) =
            (__bf16)lrelu(acc[m][n][j] + bias);
  }
  #pragma unroll
  for (int i = 0; i < 4; ++i) *((uint4*)db0 + i*256 + t) = wf2[i];
  __syncthreads();

  // q-GEMM: K=128, N=64; wave w owns rows w*32
  f32x4 qacc[2][4] = {};
  #pragma unroll
  for (int ks = 0; ks < 4; ++ks){
    bf16x8 ha[2], qb[4];
    #pragma unroll
    for (int m = 0; m < 2; ++m)
      ha[m] = *(const bf16x8*)(harea + (w*2+m)*4096 + (ks*4+lg)*256 + lr*16);
    #pragma unroll
    for (int n = 0; n < 4; ++n)
      qb[n] = *(const bf16x8*)(db0 + ((ks*4+n)*64 + l)*16);
    #pragma unroll
    for (int m = 0; m < 2; ++m)
      #pragma unroll
      for (int n = 0; n < 4; ++n)
        qacc[m][n] = mfma16(ha[m], qb[n], qacc[m][n]);
  }
  __syncthreads();   // done reading harea
  #pragma unroll
  for (int n = 0; n < 4; ++n){
    const int col = n*16 + lr;
    const float bias = f2b[a*C_ + col];
    #pragma unroll
    for (int m = 0; m < 2; ++m){
      const int rl = (w*2+m)*16;
      #pragma unroll
      for (int j = 0; j < 4; ++j)
        *(float*)(harea + ((rl + lg*4 + j)*64 + col)*4) = qacc[m][n][j] + bias;
    }
  }
  __syncthreads();
  if (t < 128){
    const int id = ids[(size_t)a*B_ + r0 + t];
    out[(size_t)a*B_ + r0 + t] = *(const float*)(harea + (t*64 + id)*4);
  }
}

extern "C" void kernel_launch(void* const* d_in, const int* in_sizes, int n_in,
                              void* d_out, int out_size, void* d_ws, size_t ws_size,
                              hipStream_t stream) {
  const float* obs  = (const float*)d_in[0];
  const float* act  = (const float*)d_in[1];
  const float* ggam = (const float*)d_in[2];
  const float* gbet = (const float*)d_in[3];
  const float* gW   = (const float*)d_in[4];
  const float* gb   = (const float*)d_in[5];
  const float* sgam = (const float*)d_in[6];
  const float* sbet = (const float*)d_in[7];
  const float* sW   = (const float*)d_in[8];
  const float* sb   = (const float*)d_in[9];
  const float* f1W  = (const float*)d_in[10];
  const float* f1b  = (const float*)d_in[11];
  const float* f2W  = (const float*)d_in[12];
  const float* f2b  = (const float*)d_in[13];
  // d_in[14]=Wq, d_in[15]=Wk dead (softmax over length-1 axis == 1)
  const float* Vm   = (const float*)d_in[16];
  float* out = (float*)d_out;

  char* base = (char*)d_ws; size_t off = 0;
  auto alloc = [&](size_t bytes) -> void* {
    off = (off + 255) & ~(size_t)255; void* p = base + off; off += bytes; return p;
  };
  float* psum   = (float*)alloc((size_t)A_*NCH*F_*4);
  float* psq    = (float*)alloc((size_t)A_*NCH*F_*4);
  float* zscale = (float*)alloc((size_t)A_*F_*4);
  float* zshift = (float*)alloc((size_t)A_*F_*4);
  float* gbp    = (float*)alloc((size_t)A_*E_*4);
  float* sbp    = (float*)alloc((size_t)A_*E_*4);
  __bf16* Bp    = (__bf16*)alloc((size_t)A_*KS_ES*16*512*2);
  __bf16* Vp    = (__bf16*)alloc((size_t)4*8*512*2);
  __bf16* B1p   = (__bf16*)alloc((size_t)A_*8*8*512*2);
  __bf16* B2p   = (__bf16*)alloc((size_t)A_*4*4*512*2);
  __bf16* si_g  = (__bf16*)alloc((size_t)A_*B_*E_*2);
  __bf16* v_g   = (__bf16*)alloc((size_t)A_*B_*E_*2);
  float* vsum   = (float*)alloc((size_t)B_*E_*4);
  int*   ids    = (int*)alloc((size_t)A_*B_*4);
  (void)ws_size; (void)in_sizes; (void)n_in; (void)out_size;

  k_stats_partial<<<dim3(NCH, A_), 320, 0, stream>>>(obs, act, psum, psq);
  k_stats_final<<<A_, F_, 0, stream>>>(psum, psq, zscale, zshift);
  k_prep<<<A_, 256, 0, stream>>>(gW, gb, ggam, gbet, sW, sb, sgam, sbet,
                                 f1W, f2W, Vm, Bp, Vp, B1p, B2p, gbp, sbp);
  k_stageA<<<dim3(B_/128, A_), 256, 0, stream>>>(obs, act, zscale, zshift,
                                                 Bp, Vp, gbp, sbp, si_g, v_g);
  k_vsum<<<(B_*E_/8)/256, 256, 0, stream>>>(v_g, vsum);
  k_ids<<<A_*B_/16, 256, 0, stream>>>(act, ids);
  k_stageC<<<dim3(B_/128, A_), 256, 0, stream>>>(si_g, v_g, vsum, B1p, B2p,
                                                 f1b, f2b, ids, out);
}